// Round 7
// baseline (274.914 us; speedup 1.0000x reference)
//
#include <hip/hip_runtime.h>

typedef __bf16 bf16;
typedef __bf16 bf16x8 __attribute__((ext_vector_type(8)));
typedef float f32x4 __attribute__((ext_vector_type(4)));

#define D_MODEL 1024
#define SEQ 2048
#define NH 16
#define HD 64

#define GLD16(gp, lp) __builtin_amdgcn_global_load_lds( \
    (const __attribute__((address_space(1))) void*)(gp), \
    (__attribute__((address_space(3))) void*)(lp), 16, 0, 0)

// sigma: frag row -> global j-local row, so S^T C-layout == P A-layout.
__device__ __forceinline__ int sigp(int r) {
    return (r & 0x23) | ((r & 0x0C) << 1) | ((r & 0x10) >> 2);
}

// ---------------- LayerNorm + bf16 cast ----------------
__global__ __launch_bounds__(256) void ln_kernel(const float* __restrict__ x,
        const float* __restrict__ g, const float* __restrict__ bta,
        bf16* __restrict__ xnb) {
    int tok = blockIdx.x;
    const float* xr = x + (size_t)tok * D_MODEL;
    float v[4];
    float s = 0.f, ss = 0.f;
#pragma unroll
    for (int j = 0; j < 4; ++j) {
        int idx = threadIdx.x + j * 256;
        float t = xr[idx];
        v[j] = t; s += t; ss += t * t;
    }
#pragma unroll
    for (int m = 32; m; m >>= 1) { s += __shfl_xor(s, m, 64); ss += __shfl_xor(ss, m, 64); }
    __shared__ float red_s[4], red_ss[4];
    int w = threadIdx.x >> 6;
    if ((threadIdx.x & 63) == 0) { red_s[w] = s; red_ss[w] = ss; }
    __syncthreads();
    s  = red_s[0] + red_s[1] + red_s[2] + red_s[3];
    ss = red_ss[0] + red_ss[1] + red_ss[2] + red_ss[3];
    float mu  = s * (1.f / D_MODEL);
    float var = ss * (1.f / D_MODEL) - mu * mu;
    float rstd = rsqrtf(var + 1e-6f);
    bf16* orow = xnb + (size_t)tok * D_MODEL;
#pragma unroll
    for (int j = 0; j < 4; ++j) {
        int idx = threadIdx.x + j * 256;
        float xn = (v[j] - mu) * rstd * g[idx] + bta[idx];
        orow[idx] = (bf16)xn;
    }
}

// ---------------- Weight transpose fp32 -> bf16 [n][k] ----------------
__global__ __launch_bounds__(256) void transpose_kernel(const float* __restrict__ W0,
        const float* __restrict__ W1, const float* __restrict__ W2,
        const float* __restrict__ W3, bf16* __restrict__ wt) {
    __shared__ float tile[32][33];
    int mat = blockIdx.z;
    const float* W = mat == 0 ? W0 : mat == 1 ? W1 : mat == 2 ? W2 : W3;
    bf16* dst = wt + (size_t)mat * D_MODEL * D_MODEL;
    int k0 = blockIdx.x * 32, n0 = blockIdx.y * 32;
    int tx = threadIdx.x & 31, ty0 = threadIdx.x >> 5;
#pragma unroll
    for (int r = 0; r < 4; ++r) {
        int ty = ty0 + r * 8;
        tile[ty][tx] = W[(size_t)(k0 + ty) * D_MODEL + n0 + tx];
    }
    __syncthreads();
#pragma unroll
    for (int r = 0; r < 4; ++r) {
        int ty = ty0 + r * 8;
        dst[(size_t)(n0 + ty) * D_MODEL + k0 + tx] = (bf16)tile[tx][ty];
    }
}

// ---------------- Fused QKV GEMM (128x128 tile, global_load_lds) ----------------
__global__ __launch_bounds__(256) void qkv_gemm(const bf16* __restrict__ A,
        const bf16* __restrict__ Bt, const float* __restrict__ bq,
        const float* __restrict__ bk, const float* __restrict__ bv,
        bf16* __restrict__ qo, bf16* __restrict__ ko, bf16* __restrict__ vto) {
    __shared__ __align__(16) bf16 As[128 * 32];
    __shared__ __align__(16) bf16 Bs[128 * 32];
    int m0 = blockIdx.x * 128, n0 = blockIdx.y * 128;
    int tid = threadIdx.x;
    int w = tid >> 6, l = tid & 63, lm = l & 15, lq = l >> 4;
    int wm = (w >> 1) * 64, wn = (w & 1) * 64;
    f32x4 acc[4][4] = {};
    const bf16* ag = A  + (size_t)(m0 + w * 32 + (l >> 2)) * D_MODEL + (l & 3) * 8;
    const bf16* bg = Bt + (size_t)(n0 + w * 32 + (l >> 2)) * D_MODEL + (l & 3) * 8;
    bf16* asd = &As[(w * 32) * 32];
    bf16* bsd = &Bs[(w * 32) * 32];
    for (int k0 = 0; k0 < D_MODEL; k0 += 32) {
        GLD16(ag,                asd);
        GLD16(ag + 16 * D_MODEL, asd + 16 * 32);
        GLD16(bg,                bsd);
        GLD16(bg + 16 * D_MODEL, bsd + 16 * 32);
        ag += 32; bg += 32;
        __syncthreads();
        bf16x8 af[4], bf_[4];
#pragma unroll
        for (int f = 0; f < 4; ++f) af[f]  = *(const bf16x8*)&As[(wm + f * 16 + lm) * 32 + lq * 8];
#pragma unroll
        for (int f = 0; f < 4; ++f) bf_[f] = *(const bf16x8*)&Bs[(wn + f * 16 + lm) * 32 + lq * 8];
#pragma unroll
        for (int fm = 0; fm < 4; ++fm)
#pragma unroll
            for (int fn = 0; fn < 4; ++fn)
                acc[fm][fn] = __builtin_amdgcn_mfma_f32_16x16x32_bf16(af[fm], bf_[fn], acc[fm][fn], 0, 0, 0);
        __syncthreads();
    }
#pragma unroll
    for (int fn = 0; fn < 4; ++fn) {
        int n_g = n0 + wn + fn * 16 + lm;
        int mat = n_g >> 10, within = n_g & 1023;
        int h = within >> 6, hdp = within & 63;
        float bias = mat == 0 ? bq[within] : mat == 1 ? bk[within] : bv[within];
#pragma unroll
        for (int fm = 0; fm < 4; ++fm) {
#pragma unroll
            for (int r = 0; r < 4; ++r) {
                int m_g = m0 + wm + fm * 16 + lq * 4 + r;
                int b_ = m_g >> 11, i = m_g & 2047;
                int bh = b_ * NH + h;
                float val = acc[fm][fn][r] + bias;
                // Q pre-scaled by 0.125 * log2(e) so attn uses exp2 directly.
                if (mat == 0)      qo [((size_t)bh * SEQ + i) * HD + hdp] = (bf16)(val * 0.180336888f);
                else if (mat == 1) ko [((size_t)bh * SEQ + i) * HD + hdp] = (bf16)val;
                else               vto[((size_t)bh * HD + hdp) * SEQ + i] = (bf16)val;
            }
        }
    }
}

// ---------------- Flash attention v5: barrier-free + XCD-pinned heads ----------------
// All 16 i-tiles of a head land on one XCD (bid&7) so its K/V stays in that
// XCD's L2 (4 heads x 512KB = 2MB < 4MB). Frag loads straight from global
// (16x64B segment gathers, L1-resident tiles). No LDS, no barriers.
__global__ __launch_bounds__(256) void attn_kernel(const bf16* __restrict__ q,
        const bf16* __restrict__ k, const bf16* __restrict__ vt,
        bf16* __restrict__ aout) {
    int bid = blockIdx.x;
    int xcd = bid & 7;
    int idx = bid >> 3;               // 0..63
    int bh  = xcd + 8 * (idx & 3);    // 4 heads pinned per XCD
    int i0  = (idx >> 2) * 128;       // 16 i-tiles
    int tid = threadIdx.x;
    int w = tid >> 6, l = tid & 63, lm = l & 15, lq = l >> 4;
    const bf16* qb = q  + (size_t)bh * SEQ * HD;
    const bf16* kb = k  + (size_t)bh * SEQ * HD;
    const bf16* vb = vt + (size_t)bh * HD * SEQ;

    bf16x8 qf[2][2];
#pragma unroll
    for (int mf = 0; mf < 2; ++mf)
#pragma unroll
        for (int kc = 0; kc < 2; ++kc)
            qf[mf][kc] = *(const bf16x8*)(qb + (size_t)(i0 + w * 32 + mf * 16 + lm) * HD + kc * 32 + lq * 8);

    // Per-lane fragment base pointers (advance by j0 each tile).
    const bf16* kpt[4]; const bf16* vpt[4];
#pragma unroll
    for (int nt = 0; nt < 4; ++nt) {
        kpt[nt] = kb + (size_t)sigp(nt * 16 + lm) * HD + lq * 8;   // + j*HD + kc*32
        vpt[nt] = vb + (size_t)(nt * 16 + lm) * SEQ + lq * 8;      // + j  + kc*32
    }

    // Prologue: K tile 0.
    bf16x8 kcur[2][4];
#pragma unroll
    for (int kc = 0; kc < 2; ++kc)
#pragma unroll
        for (int nt = 0; nt < 4; ++nt)
            kcur[kc][nt] = *(const bf16x8*)(kpt[nt] + kc * 32);

    f32x4 o[2][4] = {};
    float l_acc[2] = {0.f, 0.f};

    for (int j0 = 0; j0 < SEQ; j0 += 64) {
        // V for this tile (consumed after QK+exp).
        bf16x8 vcur[2][4];
#pragma unroll
        for (int kc = 0; kc < 2; ++kc)
#pragma unroll
            for (int nt = 0; nt < 4; ++nt)
                vcur[kc][nt] = *(const bf16x8*)(vpt[nt] + j0 + kc * 32);
        // K for next tile.
        bf16x8 knxt[2][4];
        if (j0 + 64 < SEQ) {
#pragma unroll
            for (int kc = 0; kc < 2; ++kc)
#pragma unroll
                for (int nt = 0; nt < 4; ++nt)
                    knxt[kc][nt] = *(const bf16x8*)(kpt[nt] + (size_t)(j0 + 64) * HD + kc * 32);
        }
        // S^T = K.Q^T
        f32x4 s[2][4] = {};
#pragma unroll
        for (int kc = 0; kc < 2; ++kc)
#pragma unroll
            for (int nt = 0; nt < 4; ++nt) {
                s[0][nt] = __builtin_amdgcn_mfma_f32_16x16x32_bf16(kcur[kc][nt], qf[0][kc], s[0][nt], 0, 0, 0);
                s[1][nt] = __builtin_amdgcn_mfma_f32_16x16x32_bf16(kcur[kc][nt], qf[1][kc], s[1][nt], 0, 0, 0);
            }
        // exp2 + per-lane partial sums
#pragma unroll
        for (int mf = 0; mf < 2; ++mf) {
            float psum = 0.f;
#pragma unroll
            for (int nt = 0; nt < 4; ++nt)
#pragma unroll
                for (int r = 0; r < 4; ++r) {
                    float p = exp2f(s[mf][nt][r]);
                    s[mf][nt][r] = p; psum += p;
                }
            l_acc[mf] += psum;
        }
        // P.V (P in A-layout via sigma)
#pragma unroll
        for (int kc = 0; kc < 2; ++kc) {
            bf16x8 pf[2];
#pragma unroll
            for (int mf = 0; mf < 2; ++mf)
#pragma unroll
                for (int jj = 0; jj < 8; ++jj)
                    pf[mf][jj] = (bf16)s[mf][2 * kc + (jj >> 2)][jj & 3];
#pragma unroll
            for (int nt = 0; nt < 4; ++nt) {
                o[0][nt] = __builtin_amdgcn_mfma_f32_16x16x32_bf16(pf[0], vcur[kc][nt], o[0][nt], 0, 0, 0);
                o[1][nt] = __builtin_amdgcn_mfma_f32_16x16x32_bf16(pf[1], vcur[kc][nt], o[1][nt], 0, 0, 0);
            }
        }
#pragma unroll
        for (int kc = 0; kc < 2; ++kc)
#pragma unroll
            for (int nt = 0; nt < 4; ++nt)
                kcur[kc][nt] = knxt[kc][nt];
    }
    int b_ = bh >> 4, h = bh & 15;
#pragma unroll
    for (int mf = 0; mf < 2; ++mf) {
        l_acc[mf] += __shfl_xor(l_acc[mf], 16, 64);
        l_acc[mf] += __shfl_xor(l_acc[mf], 32, 64);
        float linv[4];
#pragma unroll
        for (int r = 0; r < 4; ++r)
            linv[r] = 1.f / __shfl(l_acc[mf], lq * 4 + r, 64);
#pragma unroll
        for (int nt = 0; nt < 4; ++nt) {
#pragma unroll
            for (int r = 0; r < 4; ++r) {
                int i = i0 + w * 32 + mf * 16 + lq * 4 + r;
                int tok = b_ * SEQ + i;
                aout[(size_t)tok * D_MODEL + h * HD + nt * 16 + lm] = (bf16)(o[mf][nt][r] * linv[r]);
            }
        }
    }
}

// ---------------- Output projection + bias + residual (128x128 tile) ----------------
__global__ __launch_bounds__(256) void out_gemm(const bf16* __restrict__ A,
        const bf16* __restrict__ Bt, const float* __restrict__ bo,
        const float* __restrict__ resid, float* __restrict__ out) {
    __shared__ __align__(16) bf16 As[128 * 32];
    __shared__ __align__(16) bf16 Bs[128 * 32];
    int m0 = blockIdx.x * 128, n0 = blockIdx.y * 128;
    int tid = threadIdx.x;
    int w = tid >> 6, l = tid & 63, lm = l & 15, lq = l >> 4;
    int wm = (w >> 1) * 64, wn = (w & 1) * 64;
    f32x4 acc[4][4] = {};
    const bf16* ag = A  + (size_t)(m0 + w * 32 + (l >> 2)) * D_MODEL + (l & 3) * 8;
    const bf16* bg = Bt + (size_t)(n0 + w * 32 + (l >> 2)) * D_MODEL + (l & 3) * 8;
    bf16* asd = &As[(w * 32) * 32];
    bf16* bsd = &Bs[(w * 32) * 32];
    for (int k0 = 0; k0 < D_MODEL; k0 += 32) {
        GLD16(ag,                asd);
        GLD16(ag + 16 * D_MODEL, asd + 16 * 32);
        GLD16(bg,                bsd);
        GLD16(bg + 16 * D_MODEL, bsd + 16 * 32);
        ag += 32; bg += 32;
        __syncthreads();
        bf16x8 af[4], bf_[4];
#pragma unroll
        for (int f = 0; f < 4; ++f) af[f]  = *(const bf16x8*)&As[(wm + f * 16 + lm) * 32 + lq * 8];
#pragma unroll
        for (int f = 0; f < 4; ++f) bf_[f] = *(const bf16x8*)&Bs[(wn + f * 16 + lm) * 32 + lq * 8];
#pragma unroll
        for (int fm = 0; fm < 4; ++fm)
#pragma unroll
            for (int fn = 0; fn < 4; ++fn)
                acc[fm][fn] = __builtin_amdgcn_mfma_f32_16x16x32_bf16(af[fm], bf_[fn], acc[fm][fn], 0, 0, 0);
        __syncthreads();
    }
#pragma unroll
    for (int fn = 0; fn < 4; ++fn) {
        int n_g = n0 + wn + fn * 16 + lm;
        float bias = bo[n_g];
#pragma unroll
        for (int fm = 0; fm < 4; ++fm) {
#pragma unroll
            for (int r = 0; r < 4; ++r) {
                int m_g = m0 + wm + fm * 16 + lq * 4 + r;
                size_t idx = (size_t)m_g * D_MODEL + n_g;
                out[idx] = acc[fm][fn][r] + bias + resid[idx];
            }
        }
    }
}

extern "C" void kernel_launch(void* const* d_in, const int* in_sizes, int n_in,
                              void* d_out, int out_size, void* d_ws, size_t ws_size,
                              hipStream_t stream) {
    const float* x  = (const float*)d_in[0];
    const float* Wq = (const float*)d_in[1];
    const float* bq = (const float*)d_in[2];
    const float* Wk = (const float*)d_in[3];
    const float* bk = (const float*)d_in[4];
    const float* Wv = (const float*)d_in[5];
    const float* bv = (const float*)d_in[6];
    const float* Wo = (const float*)d_in[7];
    const float* bo = (const float*)d_in[8];
    const float* g  = (const float*)d_in[9];
    const float* bt = (const float*)d_in[10];
    (void)in_sizes; (void)n_in; (void)out_size; (void)ws_size;

    char* ws = (char*)d_ws;
    const size_t M8 = (size_t)8 << 20;
    bf16* xnb = (bf16*)(ws);            // 8 MB, reused as attn-out after qkv
    bf16* wt  = (bf16*)(ws + M8);       // 8 MB (4 x 1024x1024 bf16)
    bf16* qb  = (bf16*)(ws + 2 * M8);   // 8 MB
    bf16* kb  = (bf16*)(ws + 3 * M8);   // 8 MB
    bf16* vtb = (bf16*)(ws + 4 * M8);   // 8 MB (V^T)
    bf16* ao  = xnb;                    // alias: xnb dead after qkv_gemm
    float* out = (float*)d_out;

    ln_kernel<<<4096, 256, 0, stream>>>(x, g, bt, xnb);
    transpose_kernel<<<dim3(32, 32, 4), 256, 0, stream>>>(Wq, Wk, Wv, Wo, wt);
    qkv_gemm<<<dim3(32, 24), 256, 0, stream>>>(xnb, wt, bq, bk, bv, qb, kb, vtb);
    attn_kernel<<<512, 256, 0, stream>>>(qb, kb, vtb, ao);
    out_gemm<<<dim3(32, 8), 256, 0, stream>>>(ao, wt + (size_t)3 * D_MODEL * D_MODEL, bo, x, out);
}

// Round 9
// 217.892 us; speedup vs baseline: 1.2617x; 1.2617x over previous
//
#include <hip/hip_runtime.h>

typedef __bf16 bf16;
typedef __bf16 bf16x8 __attribute__((ext_vector_type(8)));
typedef float f32x4 __attribute__((ext_vector_type(4)));

#define D_MODEL 1024
#define SEQ 2048
#define NH 16
#define HD 64

#define GLD16(gp, lp) __builtin_amdgcn_global_load_lds( \
    (const __attribute__((address_space(1))) void*)(gp), \
    (__attribute__((address_space(3))) void*)(lp), 16, 0, 0)

// sigma^-1 for the K frag scatter (sigma: frag row -> j-local row).
__device__ __forceinline__ int sigi(int y) {
    return (y & 0x23) | ((y & 0x18) >> 1) | ((y & 0x04) << 2);
}

// ---------------- LayerNorm + bf16 cast ----------------
__global__ __launch_bounds__(256) void ln_kernel(const float* __restrict__ x,
        const float* __restrict__ g, const float* __restrict__ bta,
        bf16* __restrict__ xnb) {
    int tok = blockIdx.x;
    const float* xr = x + (size_t)tok * D_MODEL;
    float v[4];
    float s = 0.f, ss = 0.f;
#pragma unroll
    for (int j = 0; j < 4; ++j) {
        int idx = threadIdx.x + j * 256;
        float t = xr[idx];
        v[j] = t; s += t; ss += t * t;
    }
#pragma unroll
    for (int m = 32; m; m >>= 1) { s += __shfl_xor(s, m, 64); ss += __shfl_xor(ss, m, 64); }
    __shared__ float red_s[4], red_ss[4];
    int w = threadIdx.x >> 6;
    if ((threadIdx.x & 63) == 0) { red_s[w] = s; red_ss[w] = ss; }
    __syncthreads();
    s  = red_s[0] + red_s[1] + red_s[2] + red_s[3];
    ss = red_ss[0] + red_ss[1] + red_ss[2] + red_ss[3];
    float mu  = s * (1.f / D_MODEL);
    float var = ss * (1.f / D_MODEL) - mu * mu;
    float rstd = rsqrtf(var + 1e-6f);
    bf16* orow = xnb + (size_t)tok * D_MODEL;
#pragma unroll
    for (int j = 0; j < 4; ++j) {
        int idx = threadIdx.x + j * 256;
        float xn = (v[j] - mu) * rstd * g[idx] + bta[idx];
        orow[idx] = (bf16)xn;
    }
}

// ---------------- Weight transpose fp32 -> bf16 [n][k] ----------------
__global__ __launch_bounds__(256) void transpose_kernel(const float* __restrict__ W0,
        const float* __restrict__ W1, const float* __restrict__ W2,
        const float* __restrict__ W3, bf16* __restrict__ wt) {
    __shared__ float tile[32][33];
    int mat = blockIdx.z;
    const float* W = mat == 0 ? W0 : mat == 1 ? W1 : mat == 2 ? W2 : W3;
    bf16* dst = wt + (size_t)mat * D_MODEL * D_MODEL;
    int k0 = blockIdx.x * 32, n0 = blockIdx.y * 32;
    int tx = threadIdx.x & 31, ty0 = threadIdx.x >> 5;
#pragma unroll
    for (int r = 0; r < 4; ++r) {
        int ty = ty0 + r * 8;
        tile[ty][tx] = W[(size_t)(k0 + ty) * D_MODEL + n0 + tx];
    }
    __syncthreads();
#pragma unroll
    for (int r = 0; r < 4; ++r) {
        int ty = ty0 + r * 8;
        dst[(size_t)(n0 + ty) * D_MODEL + k0 + tx] = (bf16)tile[tx][ty];
    }
}

// ---------------- Fused QKV GEMM (128x128 tile, global_load_lds) ----------------
// K/V epilogue scatters into attn fragment-contiguous layout:
//   [bh][jtile][kc][nt][lane l=lq*16+lm][e:8]
// V stores vectorized (4 consecutive e_ per r-quad -> 8B stores).
__global__ __launch_bounds__(256) void qkv_gemm(const bf16* __restrict__ A,
        const bf16* __restrict__ Bt, const float* __restrict__ bq,
        const float* __restrict__ bk, const float* __restrict__ bv,
        bf16* __restrict__ qo, bf16* __restrict__ ko, bf16* __restrict__ vto) {
    __shared__ __align__(16) bf16 As[128 * 32];
    __shared__ __align__(16) bf16 Bs[128 * 32];
    int m0 = blockIdx.x * 128, n0 = blockIdx.y * 128;
    int tid = threadIdx.x;
    int w = tid >> 6, l = tid & 63, lm = l & 15, lq = l >> 4;
    int wm = (w >> 1) * 64, wn = (w & 1) * 64;
    f32x4 acc[4][4] = {};
    const bf16* ag = A  + (size_t)(m0 + w * 32 + (l >> 2)) * D_MODEL + (l & 3) * 8;
    const bf16* bg = Bt + (size_t)(n0 + w * 32 + (l >> 2)) * D_MODEL + (l & 3) * 8;
    bf16* asd = &As[(w * 32) * 32];
    bf16* bsd = &Bs[(w * 32) * 32];
    for (int k0 = 0; k0 < D_MODEL; k0 += 32) {
        GLD16(ag,                asd);
        GLD16(ag + 16 * D_MODEL, asd + 16 * 32);
        GLD16(bg,                bsd);
        GLD16(bg + 16 * D_MODEL, bsd + 16 * 32);
        ag += 32; bg += 32;
        __syncthreads();
        bf16x8 af[4], bf_[4];
#pragma unroll
        for (int f = 0; f < 4; ++f) af[f]  = *(const bf16x8*)&As[(wm + f * 16 + lm) * 32 + lq * 8];
#pragma unroll
        for (int f = 0; f < 4; ++f) bf_[f] = *(const bf16x8*)&Bs[(wn + f * 16 + lm) * 32 + lq * 8];
#pragma unroll
        for (int fm = 0; fm < 4; ++fm)
#pragma unroll
            for (int fn = 0; fn < 4; ++fn)
                acc[fm][fn] = __builtin_amdgcn_mfma_f32_16x16x32_bf16(af[fm], bf_[fn], acc[fm][fn], 0, 0, 0);
        __syncthreads();
    }
#pragma unroll
    for (int fn = 0; fn < 4; ++fn) {
        int n_g = n0 + wn + fn * 16 + lm;
        int mat = n_g >> 10, within = n_g & 1023;
        int h = within >> 6, hdp = within & 63;
        float bias = mat == 0 ? bq[within] : mat == 1 ? bk[within] : bv[within];
#pragma unroll
        for (int fm = 0; fm < 4; ++fm) {
            int mg0 = m0 + wm + fm * 16 + lq * 4;   // m_g for r=0 (mult of 4)
            int b_ = mg0 >> 11, i_base = mg0 & 2047;
            int bh = b_ * NH + h;
            if (mat == 0) {
#pragma unroll
                for (int r = 0; r < 4; ++r) {
                    float val = acc[fm][fn][r] + bias;
                    qo[((size_t)bh * SEQ + i_base + r) * HD + hdp] = (bf16)(val * 0.180336888f);
                }
            } else if (mat == 1) {
                int kc_ = hdp >> 5, lq_ = (hdp >> 3) & 3, e_ = hdp & 7;
#pragma unroll
                for (int r = 0; r < 4; ++r) {
                    int i = i_base + r;
                    int jt = i >> 6, jl = i & 63;
                    int idx = sigi(jl);
                    int nt_ = idx >> 4, lm_ = idx & 15;
                    ko[(size_t)bh * SEQ * HD + (size_t)jt * 4096 +
                       (kc_ * 4 + nt_) * 512 + (lq_ * 16 + lm_) * 8 + e_] =
                        (bf16)(acc[fm][fn][r] + bias);
                }
            } else {
                // V: 4 consecutive e_ -> one 8B store.
                int nt_ = hdp >> 4, lm_ = hdp & 15;
                int jt = i_base >> 6, jl = i_base & 63;
                int kc_ = jl >> 5, lq_ = (jl >> 3) & 3, e0 = jl & 7;
                union { bf16 a[4]; uint2 u; } pk;
#pragma unroll
                for (int r = 0; r < 4; ++r) pk.a[r] = (bf16)(acc[fm][fn][r] + bias);
                *(uint2*)&vto[(size_t)bh * SEQ * HD + (size_t)jt * 4096 +
                              (kc_ * 4 + nt_) * 512 + (lq_ * 16 + lm_) * 8 + e0] = pk.u;
            }
        }
    }
}

// ---------------- Flash attention v6: frag-contiguous loads + XCD-pinned heads ----------------
// K/V pre-swizzled to fragment order (contiguous 1KB wave-loads) AND all
// i-tiles of a head pinned to one XCD (K/V L2-resident). No LDS, no barriers.
__global__ __launch_bounds__(256) void attn_kernel(const bf16* __restrict__ q,
        const bf16* __restrict__ k, const bf16* __restrict__ vt,
        bf16* __restrict__ aout) {
    int bid = blockIdx.x;
    int xcd = bid & 7;
    int idx = bid >> 3;               // 0..63
    int bh  = xcd + 8 * (idx & 3);    // 4 heads pinned per XCD
    int i0  = (idx >> 2) * 128;       // 16 i-tiles
    int tid = threadIdx.x;
    int w = tid >> 6, l = tid & 63, lm = l & 15, lq = l >> 4;
    const bf16* qb = q  + (size_t)bh * SEQ * HD;
    const bf16* kp = k  + (size_t)bh * SEQ * HD + l * 8;
    const bf16* vp = vt + (size_t)bh * SEQ * HD + l * 8;

    bf16x8 qf[2][2];
#pragma unroll
    for (int mf = 0; mf < 2; ++mf)
#pragma unroll
        for (int kc = 0; kc < 2; ++kc)
            qf[mf][kc] = *(const bf16x8*)(qb + (size_t)(i0 + w * 32 + mf * 16 + lm) * HD + kc * 32 + lq * 8);

    // Prologue: K tile 0.
    bf16x8 kcur[2][4];
#pragma unroll
    for (int kc = 0; kc < 2; ++kc)
#pragma unroll
        for (int nt = 0; nt < 4; ++nt)
            kcur[kc][nt] = *(const bf16x8*)(kp + (kc * 4 + nt) * 512);
    kp += 4096;

    f32x4 o[2][4] = {};
    float l_acc[2] = {0.f, 0.f};

    for (int j0 = 0; j0 < SEQ; j0 += 64) {
        // V for this tile (consumed after QK+exp).
        bf16x8 vcur[2][4];
#pragma unroll
        for (int kc = 0; kc < 2; ++kc)
#pragma unroll
            for (int nt = 0; nt < 4; ++nt)
                vcur[kc][nt] = *(const bf16x8*)(vp + (kc * 4 + nt) * 512);
        vp += 4096;
        // K for next tile.
        bf16x8 knxt[2][4];
        if (j0 + 64 < SEQ) {
#pragma unroll
            for (int kc = 0; kc < 2; ++kc)
#pragma unroll
                for (int nt = 0; nt < 4; ++nt)
                    knxt[kc][nt] = *(const bf16x8*)(kp + (kc * 4 + nt) * 512);
            kp += 4096;
        }
        // S^T = K.Q^T
        f32x4 s[2][4] = {};
#pragma unroll
        for (int kc = 0; kc < 2; ++kc)
#pragma unroll
            for (int nt = 0; nt < 4; ++nt) {
                s[0][nt] = __builtin_amdgcn_mfma_f32_16x16x32_bf16(kcur[kc][nt], qf[0][kc], s[0][nt], 0, 0, 0);
                s[1][nt] = __builtin_amdgcn_mfma_f32_16x16x32_bf16(kcur[kc][nt], qf[1][kc], s[1][nt], 0, 0, 0);
            }
        // exp2 (Q pre-scaled by 0.125*log2e) + per-lane partial sums
#pragma unroll
        for (int mf = 0; mf < 2; ++mf) {
            float psum = 0.f;
#pragma unroll
            for (int nt = 0; nt < 4; ++nt)
#pragma unroll
                for (int r = 0; r < 4; ++r) {
                    float p = exp2f(s[mf][nt][r]);
                    s[mf][nt][r] = p; psum += p;
                }
            l_acc[mf] += psum;
        }
        // P.V (P in A-layout via sigma baked into K storage order)
#pragma unroll
        for (int kc = 0; kc < 2; ++kc) {
            bf16x8 pf[2];
#pragma unroll
            for (int mf = 0; mf < 2; ++mf)
#pragma unroll
                for (int jj = 0; jj < 8; ++jj)
                    pf[mf][jj] = (bf16)s[mf][2 * kc + (jj >> 2)][jj & 3];
#pragma unroll
            for (int nt = 0; nt < 4; ++nt) {
                o[0][nt] = __builtin_amdgcn_mfma_f32_16x16x32_bf16(pf[0], vcur[kc][nt], o[0][nt], 0, 0, 0);
                o[1][nt] = __builtin_amdgcn_mfma_f32_16x16x32_bf16(pf[1], vcur[kc][nt], o[1][nt], 0, 0, 0);
            }
        }
#pragma unroll
        for (int kc = 0; kc < 2; ++kc)
#pragma unroll
            for (int nt = 0; nt < 4; ++nt)
                kcur[kc][nt] = knxt[kc][nt];
    }
    int b_ = bh >> 4, h = bh & 15;
#pragma unroll
    for (int mf = 0; mf < 2; ++mf) {
        l_acc[mf] += __shfl_xor(l_acc[mf], 16, 64);
        l_acc[mf] += __shfl_xor(l_acc[mf], 32, 64);
        float linv[4];
#pragma unroll
        for (int r = 0; r < 4; ++r)
            linv[r] = 1.f / __shfl(l_acc[mf], lq * 4 + r, 64);
#pragma unroll
        for (int nt = 0; nt < 4; ++nt) {
#pragma unroll
            for (int r = 0; r < 4; ++r) {
                int i = i0 + w * 32 + mf * 16 + lq * 4 + r;
                int tok = b_ * SEQ + i;
                aout[(size_t)tok * D_MODEL + h * HD + nt * 16 + lm] = (bf16)(o[mf][nt][r] * linv[r]);
            }
        }
    }
}

// ---------------- Output projection + bias + residual (128x128 tile) ----------------
__global__ __launch_bounds__(256) void out_gemm(const bf16* __restrict__ A,
        const bf16* __restrict__ Bt, const float* __restrict__ bo,
        const float* __restrict__ resid, float* __restrict__ out) {
    __shared__ __align__(16) bf16 As[128 * 32];
    __shared__ __align__(16) bf16 Bs[128 * 32];
    int m0 = blockIdx.x * 128, n0 = blockIdx.y * 128;
    int tid = threadIdx.x;
    int w = tid >> 6, l = tid & 63, lm = l & 15, lq = l >> 4;
    int wm = (w >> 1) * 64, wn = (w & 1) * 64;
    f32x4 acc[4][4] = {};
    const bf16* ag = A  + (size_t)(m0 + w * 32 + (l >> 2)) * D_MODEL + (l & 3) * 8;
    const bf16* bg = Bt + (size_t)(n0 + w * 32 + (l >> 2)) * D_MODEL + (l & 3) * 8;
    bf16* asd = &As[(w * 32) * 32];
    bf16* bsd = &Bs[(w * 32) * 32];
    for (int k0 = 0; k0 < D_MODEL; k0 += 32) {
        GLD16(ag,                asd);
        GLD16(ag + 16 * D_MODEL, asd + 16 * 32);
        GLD16(bg,                bsd);
        GLD16(bg + 16 * D_MODEL, bsd + 16 * 32);
        ag += 32; bg += 32;
        __syncthreads();
        bf16x8 af[4], bf_[4];
#pragma unroll
        for (int f = 0; f < 4; ++f) af[f]  = *(const bf16x8*)&As[(wm + f * 16 + lm) * 32 + lq * 8];
#pragma unroll
        for (int f = 0; f < 4; ++f) bf_[f] = *(const bf16x8*)&Bs[(wn + f * 16 + lm) * 32 + lq * 8];
#pragma unroll
        for (int fm = 0; fm < 4; ++fm)
#pragma unroll
            for (int fn = 0; fn < 4; ++fn)
                acc[fm][fn] = __builtin_amdgcn_mfma_f32_16x16x32_bf16(af[fm], bf_[fn], acc[fm][fn], 0, 0, 0);
        __syncthreads();
    }
#pragma unroll
    for (int fn = 0; fn < 4; ++fn) {
        int n_g = n0 + wn + fn * 16 + lm;
        float bias = bo[n_g];
#pragma unroll
        for (int fm = 0; fm < 4; ++fm) {
#pragma unroll
            for (int r = 0; r < 4; ++r) {
                int m_g = m0 + wm + fm * 16 + lq * 4 + r;
                size_t idx = (size_t)m_g * D_MODEL + n_g;
                out[idx] = acc[fm][fn][r] + bias + resid[idx];
            }
        }
    }
}

extern "C" void kernel_launch(void* const* d_in, const int* in_sizes, int n_in,
                              void* d_out, int out_size, void* d_ws, size_t ws_size,
                              hipStream_t stream) {
    const float* x  = (const float*)d_in[0];
    const float* Wq = (const float*)d_in[1];
    const float* bq = (const float*)d_in[2];
    const float* Wk = (const float*)d_in[3];
    const float* bk = (const float*)d_in[4];
    const float* Wv = (const float*)d_in[5];
    const float* bv = (const float*)d_in[6];
    const float* Wo = (const float*)d_in[7];
    const float* bo = (const float*)d_in[8];
    const float* g  = (const float*)d_in[9];
    const float* bt = (const float*)d_in[10];
    (void)in_sizes; (void)n_in; (void)out_size; (void)ws_size;

    char* ws = (char*)d_ws;
    const size_t M8 = (size_t)8 << 20;
    bf16* xnb = (bf16*)(ws);            // 8 MB, reused as attn-out after qkv
    bf16* wt  = (bf16*)(ws + M8);       // 8 MB (4 x 1024x1024 bf16)
    bf16* qb  = (bf16*)(ws + 2 * M8);   // 8 MB
    bf16* kb  = (bf16*)(ws + 3 * M8);   // 8 MB (frag-swizzled)
    bf16* vtb = (bf16*)(ws + 4 * M8);   // 8 MB (frag-swizzled)
    bf16* ao  = xnb;                    // alias: xnb dead after qkv_gemm
    float* out = (float*)d_out;

    ln_kernel<<<4096, 256, 0, stream>>>(x, g, bt, xnb);
    transpose_kernel<<<dim3(32, 32, 4), 256, 0, stream>>>(Wq, Wk, Wv, Wo, wt);
    qkv_gemm<<<dim3(32, 24), 256, 0, stream>>>(xnb, wt, bq, bk, bv, qb, kb, vtb);
    attn_kernel<<<512, 256, 0, stream>>>(qb, kb, vtb, ao);
    out_gemm<<<dim3(32, 8), 256, 0, stream>>>(ao, wt + (size_t)3 * D_MODEL * D_MODEL, bo, x, out);
}

// Round 11
// 211.331 us; speedup vs baseline: 1.3009x; 1.0310x over previous
//
#include <hip/hip_runtime.h>

typedef __bf16 bf16;
typedef __bf16 bf16x8 __attribute__((ext_vector_type(8)));
typedef float f32x4 __attribute__((ext_vector_type(4)));

#define D_MODEL 1024
#define SEQ 2048
#define NH 16
#define HD 64

#define GLD16(gp, lp) __builtin_amdgcn_global_load_lds( \
    (const __attribute__((address_space(1))) void*)(gp), \
    (__attribute__((address_space(3))) void*)(lp), 16, 0, 0)

// sigma^-1 for the K frag scatter (sigma: frag row -> j-local row).
__device__ __forceinline__ int sigi(int y) {
    return (y & 0x23) | ((y & 0x18) >> 1) | ((y & 0x04) << 2);
}

// ---------------- LayerNorm + bf16 cast ----------------
__global__ __launch_bounds__(256) void ln_kernel(const float* __restrict__ x,
        const float* __restrict__ g, const float* __restrict__ bta,
        bf16* __restrict__ xnb) {
    int tok = blockIdx.x;
    const float* xr = x + (size_t)tok * D_MODEL;
    float v[4];
    float s = 0.f, ss = 0.f;
#pragma unroll
    for (int j = 0; j < 4; ++j) {
        int idx = threadIdx.x + j * 256;
        float t = xr[idx];
        v[j] = t; s += t; ss += t * t;
    }
#pragma unroll
    for (int m = 32; m; m >>= 1) { s += __shfl_xor(s, m, 64); ss += __shfl_xor(ss, m, 64); }
    __shared__ float red_s[4], red_ss[4];
    int w = threadIdx.x >> 6;
    if ((threadIdx.x & 63) == 0) { red_s[w] = s; red_ss[w] = ss; }
    __syncthreads();
    s  = red_s[0] + red_s[1] + red_s[2] + red_s[3];
    ss = red_ss[0] + red_ss[1] + red_ss[2] + red_ss[3];
    float mu  = s * (1.f / D_MODEL);
    float var = ss * (1.f / D_MODEL) - mu * mu;
    float rstd = rsqrtf(var + 1e-6f);
    bf16* orow = xnb + (size_t)tok * D_MODEL;
#pragma unroll
    for (int j = 0; j < 4; ++j) {
        int idx = threadIdx.x + j * 256;
        float xn = (v[j] - mu) * rstd * g[idx] + bta[idx];
        orow[idx] = (bf16)xn;
    }
}

// ---------------- Weight transpose fp32 -> bf16 [n][k] ----------------
__global__ __launch_bounds__(256) void transpose_kernel(const float* __restrict__ W0,
        const float* __restrict__ W1, const float* __restrict__ W2,
        const float* __restrict__ W3, bf16* __restrict__ wt) {
    __shared__ float tile[32][33];
    int mat = blockIdx.z;
    const float* W = mat == 0 ? W0 : mat == 1 ? W1 : mat == 2 ? W2 : W3;
    bf16* dst = wt + (size_t)mat * D_MODEL * D_MODEL;
    int k0 = blockIdx.x * 32, n0 = blockIdx.y * 32;
    int tx = threadIdx.x & 31, ty0 = threadIdx.x >> 5;
#pragma unroll
    for (int r = 0; r < 4; ++r) {
        int ty = ty0 + r * 8;
        tile[ty][tx] = W[(size_t)(k0 + ty) * D_MODEL + n0 + tx];
    }
    __syncthreads();
#pragma unroll
    for (int r = 0; r < 4; ++r) {
        int ty = ty0 + r * 8;
        dst[(size_t)(n0 + ty) * D_MODEL + k0 + tx] = (bf16)tile[tx][ty];
    }
}

// ---------------- Fused QKV GEMM (128x128 tile, global_load_lds) ----------------
// K/V epilogue scatters into attn fragment-contiguous layout:
//   [bh][jtile][kc][nt][lane l=lq*16+lm][e:8]
__global__ __launch_bounds__(256) void qkv_gemm(const bf16* __restrict__ A,
        const bf16* __restrict__ Bt, const float* __restrict__ bq,
        const float* __restrict__ bk, const float* __restrict__ bv,
        bf16* __restrict__ qo, bf16* __restrict__ ko, bf16* __restrict__ vto) {
    __shared__ __align__(16) bf16 As[128 * 32];
    __shared__ __align__(16) bf16 Bs[128 * 32];
    int m0 = blockIdx.x * 128, n0 = blockIdx.y * 128;
    int tid = threadIdx.x;
    int w = tid >> 6, l = tid & 63, lm = l & 15, lq = l >> 4;
    int wm = (w >> 1) * 64, wn = (w & 1) * 64;
    f32x4 acc[4][4] = {};
    const bf16* ag = A  + (size_t)(m0 + w * 32 + (l >> 2)) * D_MODEL + (l & 3) * 8;
    const bf16* bg = Bt + (size_t)(n0 + w * 32 + (l >> 2)) * D_MODEL + (l & 3) * 8;
    bf16* asd = &As[(w * 32) * 32];
    bf16* bsd = &Bs[(w * 32) * 32];
    for (int k0 = 0; k0 < D_MODEL; k0 += 32) {
        GLD16(ag,                asd);
        GLD16(ag + 16 * D_MODEL, asd + 16 * 32);
        GLD16(bg,                bsd);
        GLD16(bg + 16 * D_MODEL, bsd + 16 * 32);
        ag += 32; bg += 32;
        __syncthreads();
        bf16x8 af[4], bf_[4];
#pragma unroll
        for (int f = 0; f < 4; ++f) af[f]  = *(const bf16x8*)&As[(wm + f * 16 + lm) * 32 + lq * 8];
#pragma unroll
        for (int f = 0; f < 4; ++f) bf_[f] = *(const bf16x8*)&Bs[(wn + f * 16 + lm) * 32 + lq * 8];
#pragma unroll
        for (int fm = 0; fm < 4; ++fm)
#pragma unroll
            for (int fn = 0; fn < 4; ++fn)
                acc[fm][fn] = __builtin_amdgcn_mfma_f32_16x16x32_bf16(af[fm], bf_[fn], acc[fm][fn], 0, 0, 0);
        __syncthreads();
    }
#pragma unroll
    for (int fn = 0; fn < 4; ++fn) {
        int n_g = n0 + wn + fn * 16 + lm;
        int mat = n_g >> 10, within = n_g & 1023;
        int h = within >> 6, hdp = within & 63;
        float bias = mat == 0 ? bq[within] : mat == 1 ? bk[within] : bv[within];
#pragma unroll
        for (int fm = 0; fm < 4; ++fm) {
            int mg0 = m0 + wm + fm * 16 + lq * 4;   // m_g for r=0 (mult of 4)
            int b_ = mg0 >> 11, i_base = mg0 & 2047;
            int bh = b_ * NH + h;
            if (mat == 0) {
#pragma unroll
                for (int r = 0; r < 4; ++r) {
                    float val = acc[fm][fn][r] + bias;
                    qo[((size_t)bh * SEQ + i_base + r) * HD + hdp] = (bf16)(val * 0.180336888f);
                }
            } else if (mat == 1) {
                int kc_ = hdp >> 5, lq_ = (hdp >> 3) & 3, e_ = hdp & 7;
#pragma unroll
                for (int r = 0; r < 4; ++r) {
                    int i = i_base + r;
                    int jt = i >> 6, jl = i & 63;
                    int idx = sigi(jl);
                    int nt_ = idx >> 4, lm_ = idx & 15;
                    ko[(size_t)bh * SEQ * HD + (size_t)jt * 4096 +
                       (kc_ * 4 + nt_) * 512 + (lq_ * 16 + lm_) * 8 + e_] =
                        (bf16)(acc[fm][fn][r] + bias);
                }
            } else {
                // V: 4 consecutive e_ -> one 8B store.
                int nt_ = hdp >> 4, lm_ = hdp & 15;
                int jt = i_base >> 6, jl = i_base & 63;
                int kc_ = jl >> 5, lq_ = (jl >> 3) & 3, e0 = jl & 7;
                union { bf16 a[4]; uint2 u; } pk;
#pragma unroll
                for (int r = 0; r < 4; ++r) pk.a[r] = (bf16)(acc[fm][fn][r] + bias);
                *(uint2*)&vto[(size_t)bh * SEQ * HD + (size_t)jt * 4096 +
                              (kc_ * 4 + nt_) * 512 + (lq_ * 16 + lm_) * 8 + e0] = pk.u;
            }
        }
    }
}

// ---------------- Flash attention v7: j-split x2 for occupancy ----------------
// Each (head, i-tile-128) pair handled by 2 blocks (j halves) -> 1024 blocks,
// 4 blocks/CU, 4 waves/SIMD. No max-tracking => halves combine additively:
// blocks emit raw exp-weighted o (bf16) + row-sum l (fp32); combine_kernel
// finishes (o0+o1)/(l0+l1). XCD pinning: all blocks of a head on one XCD.
__global__ __launch_bounds__(256) void attn_kernel(const bf16* __restrict__ q,
        const bf16* __restrict__ k, const bf16* __restrict__ vt,
        bf16* p0, bf16* p1, float* l0o, float* l1o) {
    int bid = blockIdx.x;
    int xcd = bid & 7;
    int t = bid >> 3;                 // 0..127
    int bh = xcd + 8 * (t & 3);       // 4 heads pinned per XCD
    int t2 = t >> 2;                  // 0..31
    int i0 = (t2 >> 1) * 128;         // 16 i-tiles
    int jh = t2 & 1;                  // j half
    bf16* po = jh ? p1 : p0;
    float* lo = jh ? l1o : l0o;
    int tid = threadIdx.x;
    int w = tid >> 6, l = tid & 63, lm = l & 15, lq = l >> 4;
    const bf16* qb = q  + (size_t)bh * SEQ * HD;
    const bf16* kp = k  + (size_t)bh * SEQ * HD + (size_t)jh * (SEQ / 2) * HD + l * 8;
    const bf16* vp = vt + (size_t)bh * SEQ * HD + (size_t)jh * (SEQ / 2) * HD + l * 8;

    bf16x8 qf[2][2];
#pragma unroll
    for (int mf = 0; mf < 2; ++mf)
#pragma unroll
        for (int kc = 0; kc < 2; ++kc)
            qf[mf][kc] = *(const bf16x8*)(qb + (size_t)(i0 + w * 32 + mf * 16 + lm) * HD + kc * 32 + lq * 8);

    // Prologue: K tile 0 of this half.
    bf16x8 kcur[2][4];
#pragma unroll
    for (int kc = 0; kc < 2; ++kc)
#pragma unroll
        for (int nt = 0; nt < 4; ++nt)
            kcur[kc][nt] = *(const bf16x8*)(kp + (kc * 4 + nt) * 512);
    kp += 4096;

    f32x4 o[2][4] = {};
    float l_acc[2] = {0.f, 0.f};

    for (int j0 = 0; j0 < SEQ / 2; j0 += 64) {
        // V for this tile (consumed after QK+exp).
        bf16x8 vcur[2][4];
#pragma unroll
        for (int kc = 0; kc < 2; ++kc)
#pragma unroll
            for (int nt = 0; nt < 4; ++nt)
                vcur[kc][nt] = *(const bf16x8*)(vp + (kc * 4 + nt) * 512);
        vp += 4096;
        // K for next tile.
        bf16x8 knxt[2][4];
        if (j0 + 64 < SEQ / 2) {
#pragma unroll
            for (int kc = 0; kc < 2; ++kc)
#pragma unroll
                for (int nt = 0; nt < 4; ++nt)
                    knxt[kc][nt] = *(const bf16x8*)(kp + (kc * 4 + nt) * 512);
            kp += 4096;
        }
        // S^T = K.Q^T
        f32x4 s[2][4] = {};
#pragma unroll
        for (int kc = 0; kc < 2; ++kc)
#pragma unroll
            for (int nt = 0; nt < 4; ++nt) {
                s[0][nt] = __builtin_amdgcn_mfma_f32_16x16x32_bf16(kcur[kc][nt], qf[0][kc], s[0][nt], 0, 0, 0);
                s[1][nt] = __builtin_amdgcn_mfma_f32_16x16x32_bf16(kcur[kc][nt], qf[1][kc], s[1][nt], 0, 0, 0);
            }
        // exp2 (Q pre-scaled by 0.125*log2e) + per-lane partial sums
#pragma unroll
        for (int mf = 0; mf < 2; ++mf) {
            float psum = 0.f;
#pragma unroll
            for (int nt = 0; nt < 4; ++nt)
#pragma unroll
                for (int r = 0; r < 4; ++r) {
                    float p = exp2f(s[mf][nt][r]);
                    s[mf][nt][r] = p; psum += p;
                }
            l_acc[mf] += psum;
        }
        // P.V (P in A-layout via sigma baked into K storage order)
#pragma unroll
        for (int kc = 0; kc < 2; ++kc) {
            bf16x8 pf[2];
#pragma unroll
            for (int mf = 0; mf < 2; ++mf)
#pragma unroll
                for (int jj = 0; jj < 8; ++jj)
                    pf[mf][jj] = (bf16)s[mf][2 * kc + (jj >> 2)][jj & 3];
#pragma unroll
            for (int nt = 0; nt < 4; ++nt) {
                o[0][nt] = __builtin_amdgcn_mfma_f32_16x16x32_bf16(pf[0], vcur[kc][nt], o[0][nt], 0, 0, 0);
                o[1][nt] = __builtin_amdgcn_mfma_f32_16x16x32_bf16(pf[1], vcur[kc][nt], o[1][nt], 0, 0, 0);
            }
        }
#pragma unroll
        for (int kc = 0; kc < 2; ++kc)
#pragma unroll
            for (int nt = 0; nt < 4; ++nt)
                kcur[kc][nt] = knxt[kc][nt];
    }
    int b_ = bh >> 4, h = bh & 15;
#pragma unroll
    for (int mf = 0; mf < 2; ++mf) {
        l_acc[mf] += __shfl_xor(l_acc[mf], 16, 64);
        l_acc[mf] += __shfl_xor(l_acc[mf], 32, 64);
        // every lane now holds the full half-range l for row lm of its mf frag
        if (lq == 0)
            lo[(size_t)bh * SEQ + i0 + w * 32 + mf * 16 + lm] = l_acc[mf];
#pragma unroll
        for (int nt = 0; nt < 4; ++nt) {
#pragma unroll
            for (int r = 0; r < 4; ++r) {
                int i = i0 + w * 32 + mf * 16 + lq * 4 + r;
                int tok = b_ * SEQ + i;
                po[(size_t)tok * D_MODEL + h * HD + nt * 16 + lm] = (bf16)o[mf][nt][r];
            }
        }
    }
}

// ---------------- Combine j-halves: (o0+o1)/(l0+l1) ----------------
__global__ __launch_bounds__(256) void combine_kernel(const bf16* p0, const bf16* p1,
        const float* __restrict__ l0, const float* __restrict__ l1, bf16* aout) {
    int tok = blockIdx.x;
    int b_ = tok >> 11, i = tok & 2047;
    int col = threadIdx.x * 4;
    int h = col >> 6;
    size_t lidx = (size_t)(b_ * NH + h) * SEQ + i;
    float inv = 1.f / (l0[lidx] + l1[lidx]);
    union U { uint2 u; bf16 a[4]; } u0, u1, wr;
    size_t base = (size_t)tok * D_MODEL + col;
    u0.u = *(const uint2*)(p0 + base);
    u1.u = *(const uint2*)(p1 + base);
#pragma unroll
    for (int e = 0; e < 4; ++e)
        wr.a[e] = (bf16)(((float)u0.a[e] + (float)u1.a[e]) * inv);
    *(uint2*)(aout + base) = wr.u;
}

// ---------------- Output projection + bias + residual (128x128 tile) ----------------
__global__ __launch_bounds__(256) void out_gemm(const bf16* __restrict__ A,
        const bf16* __restrict__ Bt, const float* __restrict__ bo,
        const float* __restrict__ resid, float* __restrict__ out) {
    __shared__ __align__(16) bf16 As[128 * 32];
    __shared__ __align__(16) bf16 Bs[128 * 32];
    int m0 = blockIdx.x * 128, n0 = blockIdx.y * 128;
    int tid = threadIdx.x;
    int w = tid >> 6, l = tid & 63, lm = l & 15, lq = l >> 4;
    int wm = (w >> 1) * 64, wn = (w & 1) * 64;
    f32x4 acc[4][4] = {};
    const bf16* ag = A  + (size_t)(m0 + w * 32 + (l >> 2)) * D_MODEL + (l & 3) * 8;
    const bf16* bg = Bt + (size_t)(n0 + w * 32 + (l >> 2)) * D_MODEL + (l & 3) * 8;
    bf16* asd = &As[(w * 32) * 32];
    bf16* bsd = &Bs[(w * 32) * 32];
    for (int k0 = 0; k0 < D_MODEL; k0 += 32) {
        GLD16(ag,                asd);
        GLD16(ag + 16 * D_MODEL, asd + 16 * 32);
        GLD16(bg,                bsd);
        GLD16(bg + 16 * D_MODEL, bsd + 16 * 32);
        ag += 32; bg += 32;
        __syncthreads();
        bf16x8 af[4], bf_[4];
#pragma unroll
        for (int f = 0; f < 4; ++f) af[f]  = *(const bf16x8*)&As[(wm + f * 16 + lm) * 32 + lq * 8];
#pragma unroll
        for (int f = 0; f < 4; ++f) bf_[f] = *(const bf16x8*)&Bs[(wn + f * 16 + lm) * 32 + lq * 8];
#pragma unroll
        for (int fm = 0; fm < 4; ++fm)
#pragma unroll
            for (int fn = 0; fn < 4; ++fn)
                acc[fm][fn] = __builtin_amdgcn_mfma_f32_16x16x32_bf16(af[fm], bf_[fn], acc[fm][fn], 0, 0, 0);
        __syncthreads();
    }
#pragma unroll
    for (int fn = 0; fn < 4; ++fn) {
        int n_g = n0 + wn + fn * 16 + lm;
        float bias = bo[n_g];
#pragma unroll
        for (int fm = 0; fm < 4; ++fm) {
#pragma unroll
            for (int r = 0; r < 4; ++r) {
                int m_g = m0 + wm + fm * 16 + lq * 4 + r;
                size_t idx = (size_t)m_g * D_MODEL + n_g;
                out[idx] = acc[fm][fn][r] + bias + resid[idx];
            }
        }
    }
}

extern "C" void kernel_launch(void* const* d_in, const int* in_sizes, int n_in,
                              void* d_out, int out_size, void* d_ws, size_t ws_size,
                              hipStream_t stream) {
    const float* x  = (const float*)d_in[0];
    const float* Wq = (const float*)d_in[1];
    const float* bq = (const float*)d_in[2];
    const float* Wk = (const float*)d_in[3];
    const float* bk = (const float*)d_in[4];
    const float* Wv = (const float*)d_in[5];
    const float* bv = (const float*)d_in[6];
    const float* Wo = (const float*)d_in[7];
    const float* bo = (const float*)d_in[8];
    const float* g  = (const float*)d_in[9];
    const float* bt = (const float*)d_in[10];
    (void)in_sizes; (void)n_in; (void)out_size; (void)ws_size;

    char* ws = (char*)d_ws;
    const size_t M8 = (size_t)8 << 20;
    bf16* xnb = (bf16*)(ws);            // 8 MB; reused as attn partial-0 + combined A
    bf16* wt  = (bf16*)(ws + M8);       // 8 MB (4 x 1024x1024 bf16)
    bf16* qb  = (bf16*)(ws + 2 * M8);   // 8 MB
    bf16* kb  = (bf16*)(ws + 3 * M8);   // 8 MB (frag-swizzled)
    bf16* vtb = (bf16*)(ws + 4 * M8);   // 8 MB (frag-swizzled)
    bf16* p1  = (bf16*)(ws + 5 * M8);   // 8 MB attn partial-1
    float* l0 = (float*)(ws + 6 * M8);  // 256 KB
    float* l1 = l0 + (size_t)2 * NH * SEQ;  // 256 KB
    bf16* p0  = xnb;                    // alias: xnb dead after qkv_gemm
    float* out = (float*)d_out;

    ln_kernel<<<4096, 256, 0, stream>>>(x, g, bt, xnb);
    transpose_kernel<<<dim3(32, 32, 4), 256, 0, stream>>>(Wq, Wk, Wv, Wo, wt);
    qkv_gemm<<<dim3(32, 24), 256, 0, stream>>>(xnb, wt, bq, bk, bv, qb, kb, vtb);
    attn_kernel<<<1024, 256, 0, stream>>>(qb, kb, vtb, p0, p1, l0, l1);
    combine_kernel<<<4096, 256, 0, stream>>>(p0, p1, l0, l1, p0);
    out_gemm<<<dim3(32, 8), 256, 0, stream>>>(p0, wt + (size_t)3 * D_MODEL * D_MODEL, bo, x, out);
}